// Round 1
// baseline (5241.758 us; speedup 1.0000x reference)
//
#include <hip/hip_runtime.h>
#include <cstddef>

#define T_DIM 1024
#define S_DIM 1024
#define B_DIM 8
#define E_DIM 1024
#define H_DIM 16
#define D_DIM 64
#define NBHTD (B_DIM*H_DIM*T_DIM*D_DIM)   // 8388608 elements per [B,H,T,D] tensor

// ---------------------------------------------------------------------------
// Projection GEMM: C = A @ W^T   (A: [8192,1024] row-major, rows r = t*B+b;
// W: [out,in] row-major).  Output scattered to [B,H,T,D], optional scale.
// 128x128 tile, BK=16, 8x8 per-thread microtile, fp32.
// grid (E/128, 8192/128, 4), block 256.
// ---------------------------------------------------------------------------
__global__ __launch_bounds__(256)
void proj_kernel(const float* __restrict__ q1, const float* __restrict__ q2,
                 const float* __restrict__ key, const float* __restrict__ val,
                 const float* __restrict__ qw, const float* __restrict__ kw,
                 const float* __restrict__ vw,
                 float* __restrict__ oq1, float* __restrict__ oq2,
                 float* __restrict__ ok,  float* __restrict__ ov)
{
    const int z = blockIdx.z;
    const float* A = (z==0)?q1:(z==1)?q2:(z==2)?key:val;
    const float* W = (z<=1)?qw:(z==2)?kw:vw;
    float* O       = (z==0)?oq1:(z==1)?oq2:(z==2)?ok:ov;
    const float scale = (z<=1) ? 0.125f : 1.0f;   // D^-0.5 applied to q1,q2

    __shared__ float As[16][132];   // [k][m], pad keeps float4 alignment (132*4=528=33*16)
    __shared__ float Bs[16][132];

    const int tid = threadIdx.x;
    const int m0 = blockIdx.y * 128;
    const int n0 = blockIdx.x * 128;

    const int lrow = tid >> 1;        // 0..127
    const int lk   = (tid & 1) * 8;   // 0 or 8

    const int tx = tid & 15;
    const int ty = tid >> 4;

    float acc[8][8];
    #pragma unroll
    for (int i = 0; i < 8; ++i)
        #pragma unroll
        for (int j = 0; j < 8; ++j) acc[i][j] = 0.f;

    const float* Arow = A + (size_t)(m0 + lrow)*E_DIM + lk;
    const float* Wrow = W + (size_t)(n0 + lrow)*E_DIM + lk;

    for (int kk = 0; kk < E_DIM; kk += 16) {
        float4 a0 = *(const float4*)(Arow + kk);
        float4 a1 = *(const float4*)(Arow + kk + 4);
        float4 b0 = *(const float4*)(Wrow + kk);
        float4 b1 = *(const float4*)(Wrow + kk + 4);
        __syncthreads();
        As[lk+0][lrow]=a0.x; As[lk+1][lrow]=a0.y; As[lk+2][lrow]=a0.z; As[lk+3][lrow]=a0.w;
        As[lk+4][lrow]=a1.x; As[lk+5][lrow]=a1.y; As[lk+6][lrow]=a1.z; As[lk+7][lrow]=a1.w;
        Bs[lk+0][lrow]=b0.x; Bs[lk+1][lrow]=b0.y; Bs[lk+2][lrow]=b0.z; Bs[lk+3][lrow]=b0.w;
        Bs[lk+4][lrow]=b1.x; Bs[lk+5][lrow]=b1.y; Bs[lk+6][lrow]=b1.z; Bs[lk+7][lrow]=b1.w;
        __syncthreads();
        #pragma unroll
        for (int k = 0; k < 16; ++k) {
            float4 av0 = *(const float4*)&As[k][ty*8];
            float4 av1 = *(const float4*)&As[k][ty*8+4];
            float4 bv0 = *(const float4*)&Bs[k][tx*8];
            float4 bv1 = *(const float4*)&Bs[k][tx*8+4];
            float a[8] = {av0.x,av0.y,av0.z,av0.w,av1.x,av1.y,av1.z,av1.w};
            float b[8] = {bv0.x,bv0.y,bv0.z,bv0.w,bv1.x,bv1.y,bv1.z,bv1.w};
            #pragma unroll
            for (int i = 0; i < 8; ++i)
                #pragma unroll
                for (int j = 0; j < 8; ++j) acc[i][j] += a[i]*b[j];
        }
    }

    // scatter-store to [B,H,T,D]; one thread's 8 cols sit inside one head (8 | 64)
    const int hcol = (n0 + tx*8) >> 6;
    const int dloc = (n0 + tx*8) & 63;
    #pragma unroll
    for (int i = 0; i < 8; ++i) {
        int r = m0 + ty*8 + i;
        int t = r >> 3, bb = r & 7;
        float* dst = O + (((size_t)(bb*H_DIM + hcol)*T_DIM) + t)*D_DIM + dloc;
        *(float4*)dst     = make_float4(acc[i][0]*scale, acc[i][1]*scale,
                                        acc[i][2]*scale, acc[i][3]*scale);
        *(float4*)(dst+4) = make_float4(acc[i][4]*scale, acc[i][5]*scale,
                                        acc[i][6]*scale, acc[i][7]*scale);
    }
}

// ---------------------------------------------------------------------------
// Output projection: C = merge(O) @ ow^T, merge gathers [B,H,T,D] -> [T*B, E].
// Same tile structure; direct row-major store to [T,B,E].
// grid (8, 64, 2) : z=0 -> (Od -> outd), z=1 -> (Os -> outs)
// ---------------------------------------------------------------------------
__global__ __launch_bounds__(256)
void outproj_kernel(const float* __restrict__ Od, const float* __restrict__ Os,
                    const float* __restrict__ ow,
                    float* __restrict__ outd, float* __restrict__ outs)
{
    const int z = blockIdx.z;
    const float* Ain = z ? Os : Od;
    float* Out       = z ? outs : outd;

    __shared__ float As[16][132];
    __shared__ float Bs[16][132];

    const int tid = threadIdx.x;
    const int m0 = blockIdx.y * 128;
    const int n0 = blockIdx.x * 128;

    const int lrow = tid >> 1;
    const int lk   = (tid & 1) * 8;
    const int tx = tid & 15;
    const int ty = tid >> 4;

    const int r_ld = m0 + lrow;
    const int tt = r_ld >> 3;
    const int bb_ld = r_ld & 7;

    float acc[8][8];
    #pragma unroll
    for (int i = 0; i < 8; ++i)
        #pragma unroll
        for (int j = 0; j < 8; ++j) acc[i][j] = 0.f;

    const float* Wrow = ow + (size_t)(n0 + lrow)*E_DIM + lk;

    for (int kk = 0; kk < E_DIM; kk += 16) {
        const int k0 = kk + lk;
        const int h0 = k0 >> 6;
        const int d0 = k0 & 63;          // <=56, so d0..d0+7 stays in one head
        const float* ap = Ain + (((size_t)(bb_ld*H_DIM + h0)*T_DIM) + tt)*D_DIM + d0;
        float4 a0 = *(const float4*)ap;
        float4 a1 = *(const float4*)(ap + 4);
        float4 b0 = *(const float4*)(Wrow + kk);
        float4 b1 = *(const float4*)(Wrow + kk + 4);
        __syncthreads();
        As[lk+0][lrow]=a0.x; As[lk+1][lrow]=a0.y; As[lk+2][lrow]=a0.z; As[lk+3][lrow]=a0.w;
        As[lk+4][lrow]=a1.x; As[lk+5][lrow]=a1.y; As[lk+6][lrow]=a1.z; As[lk+7][lrow]=a1.w;
        Bs[lk+0][lrow]=b0.x; Bs[lk+1][lrow]=b0.y; Bs[lk+2][lrow]=b0.z; Bs[lk+3][lrow]=b0.w;
        Bs[lk+4][lrow]=b1.x; Bs[lk+5][lrow]=b1.y; Bs[lk+6][lrow]=b1.z; Bs[lk+7][lrow]=b1.w;
        __syncthreads();
        #pragma unroll
        for (int k = 0; k < 16; ++k) {
            float4 av0 = *(const float4*)&As[k][ty*8];
            float4 av1 = *(const float4*)&As[k][ty*8+4];
            float4 bv0 = *(const float4*)&Bs[k][tx*8];
            float4 bv1 = *(const float4*)&Bs[k][tx*8+4];
            float a[8] = {av0.x,av0.y,av0.z,av0.w,av1.x,av1.y,av1.z,av1.w};
            float b[8] = {bv0.x,bv0.y,bv0.z,bv0.w,bv1.x,bv1.y,bv1.z,bv1.w};
            #pragma unroll
            for (int i = 0; i < 8; ++i)
                #pragma unroll
                for (int j = 0; j < 8; ++j) acc[i][j] += a[i]*b[j];
        }
    }

    #pragma unroll
    for (int i = 0; i < 8; ++i) {
        int r = m0 + ty*8 + i;
        float* dst = Out + (size_t)r*E_DIM + n0 + tx*8;
        *(float4*)dst     = make_float4(acc[i][0],acc[i][1],acc[i][2],acc[i][3]);
        *(float4*)(dst+4) = make_float4(acc[i][4],acc[i][5],acc[i][6],acc[i][7]);
    }
}

// ---------------------------------------------------------------------------
// Attention pass (one stream).  Workgroup = (b, 8 query rows), loops all H
// heads; head-mean of probs accumulated in registers (no atomics).
// Mask semantics: masked (s > t) scores are REPLACED by 1e-30 before softmax
// (reference uses MASK_FILL=1e-30, not -inf).
// grid (T/8=128, B=8), block 256.  LDS = 32KB scores + 8KB scratch = 40KB.
// ---------------------------------------------------------------------------
__global__ __launch_bounds__(256)
void attn_kernel(const float* __restrict__ Qh, const float* __restrict__ Kh,
                 const float* __restrict__ Vh, float* __restrict__ Oout,
                 float* __restrict__ attn_mean)
{
    const int b  = blockIdx.y;
    const int t0 = blockIdx.x * 8;
    const int tid  = threadIdx.x;
    const int lane = tid & 63;
    const int wave = tid >> 6;

    __shared__ float sc[8][S_DIM];     // probs/scores, 32 KB
    __shared__ float pool[2048];       // 8 KB, aliased: qs (512 f) / pvred (2048 f)
    float (*qs)[D_DIM]       = (float (*)[D_DIM])pool;
    float (*pvred)[8][D_DIM] = (float (*)[8][D_DIM])pool;

    float accm[32];
    #pragma unroll
    for (int j = 0; j < 32; ++j) accm[j] = 0.f;
    const int i_acc = tid >> 5;   // row 0..7
    const int c_acc = tid & 31;

    #pragma unroll 1
    for (int h = 0; h < H_DIM; ++h) {
        const int bh = b*H_DIM + h;
        const float* Kb = Kh + (size_t)bh*S_DIM*D_DIM;
        const float* Vb = Vh + (size_t)bh*S_DIM*D_DIM;

        // ---- load 8 Q rows (already scaled) ----
        if (tid < 128) {
            int i = tid >> 4;
            int d4 = (tid & 15) * 4;
            *(float4*)&qs[i][d4] =
                *(const float4*)(Qh + ((size_t)bh*T_DIM + t0 + i)*D_DIM + d4);
        }
        __syncthreads();

        // ---- scores: each thread owns 4 K rows, dots vs 8 Q rows ----
        #pragma unroll 1
        for (int j = 0; j < 4; ++j) {
            const int s = j*256 + tid;
            const float4* kr = (const float4*)(Kb + (size_t)s*D_DIM);
            float accs[8] = {0,0,0,0,0,0,0,0};
            #pragma unroll
            for (int d4 = 0; d4 < 16; ++d4) {
                float4 kv = kr[d4];
                const int d = d4*4;
                #pragma unroll
                for (int i = 0; i < 8; ++i) {
                    accs[i] += kv.x*qs[i][d]   + kv.y*qs[i][d+1]
                             + kv.z*qs[i][d+2] + kv.w*qs[i][d+3];
                }
            }
            #pragma unroll
            for (int i = 0; i < 8; ++i)
                sc[i][s] = (s > t0 + i) ? 1e-30f : accs[i];
        }
        __syncthreads();

        // ---- softmax: each wave handles 2 rows ----
        #pragma unroll 1
        for (int r = 0; r < 2; ++r) {
            const int i = wave*2 + r;
            float vbuf[16];
            float m = -3.0e38f;
            #pragma unroll
            for (int c = 0; c < 16; ++c) {
                vbuf[c] = sc[i][lane + c*64];
                m = fmaxf(m, vbuf[c]);
            }
            #pragma unroll
            for (int off = 32; off > 0; off >>= 1) m = fmaxf(m, __shfl_xor(m, off, 64));
            float sum = 0.f;
            #pragma unroll
            for (int c = 0; c < 16; ++c) {
                float e = __expf(vbuf[c] - m);
                vbuf[c] = e;
                sum += e;
            }
            #pragma unroll
            for (int off = 32; off > 0; off >>= 1) sum += __shfl_xor(sum, off, 64);
            const float inv = 1.0f / sum;
            #pragma unroll
            for (int c = 0; c < 16; ++c) sc[i][lane + c*64] = vbuf[c]*inv;
        }
        __syncthreads();

        // ---- accumulate head-mean of probs in registers ----
        #pragma unroll
        for (int j = 0; j < 32; ++j) accm[j] += sc[i_acc][c_acc + 32*j];

        // ---- PV: wave w covers s in [w*256,(w+1)*256), lanes over d ----
        {
            const float* vb = Vb + (size_t)(wave*256)*D_DIM + lane;
            float o[8] = {0,0,0,0,0,0,0,0};
            #pragma unroll 2
            for (int s4 = 0; s4 < 256; s4 += 4) {
                float v0 = vb[(s4+0)*D_DIM];
                float v1 = vb[(s4+1)*D_DIM];
                float v2 = vb[(s4+2)*D_DIM];
                float v3 = vb[(s4+3)*D_DIM];
                const int sg = wave*256 + s4;
                #pragma unroll
                for (int i = 0; i < 8; ++i) {
                    float4 p = *(const float4*)&sc[i][sg];   // uniform -> broadcast
                    o[i] += p.x*v0 + p.y*v1 + p.z*v2 + p.w*v3;
                }
            }
            #pragma unroll
            for (int i = 0; i < 8; ++i) pvred[wave][i][lane] = o[i];
        }
        __syncthreads();

        // ---- cross-wave reduce + store O ----
        #pragma unroll
        for (int rr = 0; rr < 2; ++rr) {
            int idx = tid + rr*256;
            int i = idx >> 6, d = idx & 63;
            float vsum = pvred[0][i][d] + pvred[1][i][d]
                       + pvred[2][i][d] + pvred[3][i][d];
            Oout[((size_t)bh*T_DIM + t0 + i)*D_DIM + d] = vsum;
        }
        __syncthreads();
    }

    // ---- write head-mean ----
    #pragma unroll
    for (int j = 0; j < 32; ++j) {
        attn_mean[((size_t)b*T_DIM + (t0 + i_acc))*S_DIM + c_acc + 32*j]
            = accm[j] * (1.0f/H_DIM);
    }
}

// ---------------------------------------------------------------------------
// k2 = k + o_s ; v2 = v + o_s   (in place)
// ---------------------------------------------------------------------------
__global__ __launch_bounds__(256)
void add_kernel(float* __restrict__ K, float* __restrict__ V,
                const float* __restrict__ O)
{
    size_t i = ((size_t)blockIdx.x*256 + threadIdx.x)*4;
    float4 o = *(const float4*)(O+i);
    float4 k = *(const float4*)(K+i);
    float4 v = *(const float4*)(V+i);
    k.x+=o.x; k.y+=o.y; k.z+=o.z; k.w+=o.w;
    v.x+=o.x; v.y+=o.y; v.z+=o.z; v.w+=o.w;
    *(float4*)(K+i)=k;
    *(float4*)(V+i)=v;
}

// ---------------------------------------------------------------------------
extern "C" void kernel_launch(void* const* d_in, const int* in_sizes, int n_in,
                              void* d_out, int out_size, void* d_ws, size_t ws_size,
                              hipStream_t stream)
{
    const float* q1  = (const float*)d_in[0];
    const float* q2  = (const float*)d_in[1];
    const float* key = (const float*)d_in[2];
    const float* val = (const float*)d_in[3];
    // d_in[4] = attn_mask: causal triu(k=1); computed analytically (s > t)
    const float* qw  = (const float*)d_in[5];
    const float* kw  = (const float*)d_in[6];
    const float* vw  = (const float*)d_in[7];
    const float* ow  = (const float*)d_in[8];

    float* out   = (float*)d_out;
    float* outd  = out;               // attn_output_d  [T,B,E]
    float* attnd = out + 1*(size_t)NBHTD; // attn_d     [B,T,S]
    float* outs  = out + 2*(size_t)NBHTD; // attn_output_s
    float* attns = out + 3*(size_t)NBHTD; // attn_s

    float* ws  = (float*)d_ws;            // 4 x 32MB = 128 MB
    float* Kh  = ws;
    float* Vh  = ws + 1*(size_t)NBHTD;
    float* Osb = ws + 2*(size_t)NBHTD;
    float* Odb = ws + 3*(size_t)NBHTD;
    // Q projections borrow the attn_output regions of d_out (dead until outproj)
    float* Q1h = outd;
    float* Q2h = outs;

    proj_kernel<<<dim3(8, 64, 4), 256, 0, stream>>>(q1, q2, key, val, qw, kw, vw,
                                                    Q1h, Q2h, Kh, Vh);
    attn_kernel<<<dim3(128, 8), 256, 0, stream>>>(Q2h, Kh, Vh, Osb, attns);
    add_kernel<<<NBHTD/4/256, 256, 0, stream>>>(Kh, Vh, Osb);
    attn_kernel<<<dim3(128, 8), 256, 0, stream>>>(Q1h, Kh, Vh, Odb, attnd);
    outproj_kernel<<<dim3(8, 64, 2), 256, 0, stream>>>(Odb, Osb, ow, outd, outs);
}

// Round 2
// 2571.301 us; speedup vs baseline: 2.0386x; 2.0386x over previous
//
#include <hip/hip_runtime.h>
#include <cstddef>

#define T_DIM 1024
#define S_DIM 1024
#define B_DIM 8
#define E_DIM 1024
#define H_DIM 16
#define D_DIM 64
#define NBHTD (B_DIM*H_DIM*T_DIM*D_DIM)   // 8388608 elements per [B,H,T,D] tensor

typedef __attribute__((ext_vector_type(8))) short short8;
typedef __attribute__((ext_vector_type(4))) float floatx4;

// ---- bf16 helpers (RNE via bit ops; no NaN inputs here) ----
__device__ inline unsigned short f2bf(float x){
    union { float f; unsigned u; } v; v.f = x;
    unsigned r = (v.u + 0x7FFFu + ((v.u >> 16) & 1u)) >> 16;
    return (unsigned short)r;
}
__device__ inline float bf2f(unsigned short h){
    union { float f; unsigned u; } v; v.u = ((unsigned)h) << 16; return v.f;
}

// LDS swizzle for the 16x1024 fp32 score/prob buffer: XOR of the 16B chunk
// index with (row&7).  Keeps every access >= 2-way-clean (see analysis).
__device__ inline int swz(int row, int s){
    int ch = (s >> 2) ^ (row & 7);
    return (row << 10) + (ch << 2) + (s & 3);
}

// ---------------------------------------------------------------------------
// Projection GEMM: C = A @ W^T.  z=0/1: q1,q2 (scaled, fp32 out); z=2: key ->
// bf16 hi/lo split [B,H,S,D]; z=3: value -> fp32 [B,H,S,D].
// 128x128 tile, BK=16, 8x8 microtile.  grid (8, 64, 4), block 256.
// ---------------------------------------------------------------------------
__global__ __launch_bounds__(256)
void proj_kernel(const float* __restrict__ q1, const float* __restrict__ q2,
                 const float* __restrict__ key, const float* __restrict__ val,
                 const float* __restrict__ qw, const float* __restrict__ kw,
                 const float* __restrict__ vw,
                 float* __restrict__ oq1, float* __restrict__ oq2,
                 unsigned short* __restrict__ khi, unsigned short* __restrict__ klo,
                 float* __restrict__ ovh)
{
    const int z = blockIdx.z;
    const float* A = (z==0)?q1:(z==1)?q2:(z==2)?key:val;
    const float* W = (z<=1)?qw:(z==2)?kw:vw;
    const float scale = (z<=1) ? 0.125f : 1.0f;

    __shared__ float As[16][132];
    __shared__ float Bs[16][132];

    const int tid = threadIdx.x;
    const int m0 = blockIdx.y * 128;
    const int n0 = blockIdx.x * 128;

    const int lrow = tid >> 1;
    const int lk   = (tid & 1) * 8;
    const int tx = tid & 15;
    const int ty = tid >> 4;

    float acc[8][8];
    #pragma unroll
    for (int i = 0; i < 8; ++i)
        #pragma unroll
        for (int j = 0; j < 8; ++j) acc[i][j] = 0.f;

    const float* Arow = A + (size_t)(m0 + lrow)*E_DIM + lk;
    const float* Wrow = W + (size_t)(n0 + lrow)*E_DIM + lk;

    for (int kk = 0; kk < E_DIM; kk += 16) {
        float4 a0 = *(const float4*)(Arow + kk);
        float4 a1 = *(const float4*)(Arow + kk + 4);
        float4 b0 = *(const float4*)(Wrow + kk);
        float4 b1 = *(const float4*)(Wrow + kk + 4);
        __syncthreads();
        As[lk+0][lrow]=a0.x; As[lk+1][lrow]=a0.y; As[lk+2][lrow]=a0.z; As[lk+3][lrow]=a0.w;
        As[lk+4][lrow]=a1.x; As[lk+5][lrow]=a1.y; As[lk+6][lrow]=a1.z; As[lk+7][lrow]=a1.w;
        Bs[lk+0][lrow]=b0.x; Bs[lk+1][lrow]=b0.y; Bs[lk+2][lrow]=b0.z; Bs[lk+3][lrow]=b0.w;
        Bs[lk+4][lrow]=b1.x; Bs[lk+5][lrow]=b1.y; Bs[lk+6][lrow]=b1.z; Bs[lk+7][lrow]=b1.w;
        __syncthreads();
        #pragma unroll
        for (int k = 0; k < 16; ++k) {
            float4 av0 = *(const float4*)&As[k][ty*8];
            float4 av1 = *(const float4*)&As[k][ty*8+4];
            float4 bv0 = *(const float4*)&Bs[k][tx*8];
            float4 bv1 = *(const float4*)&Bs[k][tx*8+4];
            float a[8] = {av0.x,av0.y,av0.z,av0.w,av1.x,av1.y,av1.z,av1.w};
            float b[8] = {bv0.x,bv0.y,bv0.z,bv0.w,bv1.x,bv1.y,bv1.z,bv1.w};
            #pragma unroll
            for (int i = 0; i < 8; ++i)
                #pragma unroll
                for (int j = 0; j < 8; ++j) acc[i][j] += a[i]*b[j];
        }
    }

    const int hcol = (n0 + tx*8) >> 6;
    const int dloc = (n0 + tx*8) & 63;

    if (z == 2) {
        // bf16 hi/lo split store to Khi/Klo [B,H,S,D]
        #pragma unroll
        for (int i = 0; i < 8; ++i) {
            int r = m0 + ty*8 + i;
            int t = r >> 3, bb = r & 7;
            size_t base = (((size_t)(bb*H_DIM + hcol)*T_DIM) + t)*D_DIM + dloc;
            short8 h8, l8;
            #pragma unroll
            for (int j = 0; j < 8; ++j) {
                unsigned short hh = f2bf(acc[i][j]);
                h8[j] = (short)hh;
                l8[j] = (short)f2bf(acc[i][j] - bf2f(hh));
            }
            *(short8*)(khi + base) = h8;
            *(short8*)(klo + base) = l8;
        }
    } else {
        float* O = (z==0)?oq1:(z==1)?oq2:ovh;
        #pragma unroll
        for (int i = 0; i < 8; ++i) {
            int r = m0 + ty*8 + i;
            int t = r >> 3, bb = r & 7;
            float* dst = O + (((size_t)(bb*H_DIM + hcol)*T_DIM) + t)*D_DIM + dloc;
            *(float4*)dst     = make_float4(acc[i][0]*scale, acc[i][1]*scale,
                                            acc[i][2]*scale, acc[i][3]*scale);
            *(float4*)(dst+4) = make_float4(acc[i][4]*scale, acc[i][5]*scale,
                                            acc[i][6]*scale, acc[i][7]*scale);
        }
    }
}

// ---------------------------------------------------------------------------
// Split+transpose V: fp32 [B,H,S,D] -> bf16 hi/lo [B,H,D,S].
// grid (S/64=16, B*H=128), block 256.
// ---------------------------------------------------------------------------
__global__ __launch_bounds__(256)
void split_vt(const float* __restrict__ Vh, unsigned short* __restrict__ Vthi,
              unsigned short* __restrict__ Vtlo)
{
    __shared__ float tile[64][68];
    const int bh = blockIdx.y, s0 = blockIdx.x*64;
    const int tid = threadIdx.x;
    const size_t base = (size_t)bh*S_DIM*D_DIM;

    {
        int r = tid >> 2, c0 = (tid & 3) * 16;
        const float* p = Vh + base + (size_t)(s0 + r)*D_DIM + c0;
        float4 a = *(const float4*)p;
        float4 b = *(const float4*)(p+4);
        float4 c = *(const float4*)(p+8);
        float4 d = *(const float4*)(p+12);
        *(float4*)&tile[r][c0]    = a;
        *(float4*)&tile[r][c0+4]  = b;
        *(float4*)&tile[r][c0+8]  = c;
        *(float4*)&tile[r][c0+12] = d;
    }
    __syncthreads();
    {
        int d = tid >> 2, cs = (tid & 3) * 16;
        short8 hi[2], lo[2];
        #pragma unroll
        for (int half = 0; half < 2; ++half)
            #pragma unroll
            for (int u = 0; u < 8; ++u) {
                float x = tile[cs + half*8 + u][d];
                unsigned short hh = f2bf(x);
                hi[half][u] = (short)hh;
                lo[half][u] = (short)f2bf(x - bf2f(hh));
            }
        size_t obase = base + (size_t)d*S_DIM + s0 + cs;
        *(short8*)(Vthi + obase)     = hi[0];
        *(short8*)(Vthi + obase + 8) = hi[1];
        *(short8*)(Vtlo + obase)     = lo[0];
        *(short8*)(Vtlo + obase + 8) = lo[1];
    }
}

// ---------------------------------------------------------------------------
// MFMA attention pass (one stream), bf16x3 scores / bf16x2 PV.
// Block: 16 q-rows, loops all 16 heads; head-mean kept in registers (fused
// into softmax).  Mask: masked (s>t) scores REPLACED by 1e-30 pre-softmax.
// grid (64, 8), block 256, LDS 64KB -> 2 blocks/CU, whole grid co-resident.
// ---------------------------------------------------------------------------
__global__ __launch_bounds__(256, 2)
void attn_mfma(const float* __restrict__ Qh,
               const unsigned short* __restrict__ Khi, const unsigned short* __restrict__ Klo,
               const unsigned short* __restrict__ Vthi, const unsigned short* __restrict__ Vtlo,
               float* __restrict__ Oout, float* __restrict__ attn_mean)
{
    const int b  = blockIdx.y;
    const int t0 = blockIdx.x * 16;
    const int tid  = threadIdx.x;
    const int lane = tid & 63;
    const int wave = tid >> 6;
    const int lrow = lane & 15;
    const int quad = lane >> 4;

    __shared__ float sc[16 * 1024];   // 64 KB, swizzled

    // head-mean accumulators: wave w owns rows 4w..4w+3; lane owns cols
    // {lane*2 + 128c, lane*2+1 + 128c}, c=0..7
    float accm[4][16];
    #pragma unroll
    for (int j = 0; j < 4; ++j)
        #pragma unroll
        for (int c = 0; c < 16; ++c) accm[j][c] = 0.f;

    #pragma unroll 1
    for (int h = 0; h < H_DIM; ++h) {
        const int bh = b*H_DIM + h;
        const size_t kbase = (size_t)bh * S_DIM * D_DIM;

        // ---- Q fragments (A-layout), bf16 hi/lo, k0 = 0 and 32 ----
        short8 qh0, ql0, qh1, ql1;
        {
            const float* qp = Qh + kbase + (size_t)(t0 + lrow)*D_DIM + quad*8;
            float4 a  = *(const float4*)qp;
            float4 b4 = *(const float4*)(qp+4);
            float4 c4 = *(const float4*)(qp+32);
            float4 d4 = *(const float4*)(qp+36);
            float va[8] = {a.x,a.y,a.z,a.w,b4.x,b4.y,b4.z,b4.w};
            float vb8[8] = {c4.x,c4.y,c4.z,c4.w,d4.x,d4.y,d4.z,d4.w};
            #pragma unroll
            for (int j = 0; j < 8; ++j) {
                unsigned short h0 = f2bf(va[j]);
                qh0[j] = (short)h0; ql0[j] = (short)f2bf(va[j] - bf2f(h0));
                unsigned short h1 = f2bf(vb8[j]);
                qh1[j] = (short)h1; ql1[j] = (short)f2bf(vb8[j] - bf2f(h1));
            }
        }

        __syncthreads();   // sc free (previous head's PV reads done)

        // ---- scores: wave w covers s in [w*256,(w+1)*256), 16 tiles ----
        #pragma unroll 1
        for (int jt = 0; jt < 16; ++jt) {
            const int s0 = wave*256 + jt*16;
            const unsigned short* kp_h = Khi + kbase + (size_t)(s0 + lrow)*D_DIM + quad*8;
            const unsigned short* kp_l = Klo + kbase + (size_t)(s0 + lrow)*D_DIM + quad*8;
            short8 kh0 = *(const short8*)(kp_h);
            short8 kh1 = *(const short8*)(kp_h + 32);
            short8 kl0 = *(const short8*)(kp_l);
            short8 kl1 = *(const short8*)(kp_l + 32);
            floatx4 acc = {0.f,0.f,0.f,0.f};
            acc = __builtin_amdgcn_mfma_f32_16x16x32_bf16(qh0, kh0, acc, 0,0,0);
            acc = __builtin_amdgcn_mfma_f32_16x16x32_bf16(qh1, kh1, acc, 0,0,0);
            acc = __builtin_amdgcn_mfma_f32_16x16x32_bf16(qh0, kl0, acc, 0,0,0);
            acc = __builtin_amdgcn_mfma_f32_16x16x32_bf16(qh1, kl1, acc, 0,0,0);
            acc = __builtin_amdgcn_mfma_f32_16x16x32_bf16(ql0, kh0, acc, 0,0,0);
            acc = __builtin_amdgcn_mfma_f32_16x16x32_bf16(ql1, kh1, acc, 0,0,0);
            const int s_g = s0 + lrow;
            #pragma unroll
            for (int r = 0; r < 4; ++r) {
                int q = quad*4 + r;                      // C-layout: row=quad*4+reg
                float v = (s_g > t0 + q) ? 1e-30f : acc[r];
                sc[swz(q, s_g)] = v;
            }
        }
        __syncthreads();

        // ---- softmax (+ fused head-mean accumulate): wave w -> rows 4w+j ----
        #pragma unroll 1
        for (int j = 0; j < 4; ++j) {
            const int row = wave*4 + j;
            float2 vb[8];
            float m = -3.0e38f;
            #pragma unroll
            for (int c = 0; c < 8; ++c) {
                int s = lane*2 + 128*c;
                vb[c] = *(const float2*)&sc[swz(row, s)];
                m = fmaxf(m, fmaxf(vb[c].x, vb[c].y));
            }
            #pragma unroll
            for (int off = 32; off > 0; off >>= 1) m = fmaxf(m, __shfl_xor(m, off));
            float sum = 0.f;
            #pragma unroll
            for (int c = 0; c < 8; ++c) {
                vb[c].x = __expf(vb[c].x - m);
                vb[c].y = __expf(vb[c].y - m);
                sum += vb[c].x + vb[c].y;
            }
            #pragma unroll
            for (int off = 32; off > 0; off >>= 1) sum += __shfl_xor(sum, off);
            const float inv = 1.0f / sum;
            #pragma unroll
            for (int c = 0; c < 8; ++c) {
                int s = lane*2 + 128*c;
                float p0 = vb[c].x * inv, p1 = vb[c].y * inv;
                accm[j][2*c]   += p0;
                accm[j][2*c+1] += p1;
                float2 pw; pw.x = p0; pw.y = p1;
                *(float2*)&sc[swz(row, s)] = pw;
            }
        }
        __syncthreads();

        // ---- PV: wave w owns d-block [16w,16w+16); K-loop over s ----
        {
            const int d0 = wave*16;
            const unsigned short* vh = Vthi + kbase + (size_t)(d0 + lrow)*S_DIM;
            const unsigned short* vl = Vtlo + kbase + (size_t)(d0 + lrow)*S_DIM;
            floatx4 oa = {0.f,0.f,0.f,0.f}, ob = {0.f,0.f,0.f,0.f};
            #pragma unroll 2
            for (int sk = 0; sk < S_DIM; sk += 32) {
                const int sa = sk + quad*8;
                float4 p0 = *(const float4*)&sc[swz(lrow, sa)];
                float4 p1 = *(const float4*)&sc[swz(lrow, sa+4)];
                short8 af;
                af[0]=(short)f2bf(p0.x); af[1]=(short)f2bf(p0.y);
                af[2]=(short)f2bf(p0.z); af[3]=(short)f2bf(p0.w);
                af[4]=(short)f2bf(p1.x); af[5]=(short)f2bf(p1.y);
                af[6]=(short)f2bf(p1.z); af[7]=(short)f2bf(p1.w);
                short8 bh8 = *(const short8*)(vh + sa);
                short8 bl8 = *(const short8*)(vl + sa);
                oa = __builtin_amdgcn_mfma_f32_16x16x32_bf16(af, bh8, oa, 0,0,0);
                ob = __builtin_amdgcn_mfma_f32_16x16x32_bf16(af, bl8, ob, 0,0,0);
            }
            #pragma unroll
            for (int r = 0; r < 4; ++r) {
                int q = quad*4 + r;
                Oout[kbase + (size_t)(t0+q)*D_DIM + d0 + lrow] = oa[r] + ob[r];
            }
        }
    }

    // ---- head-mean write: [B,T,S] ----
    #pragma unroll
    for (int j = 0; j < 4; ++j) {
        int row = wave*4 + j;
        #pragma unroll
        for (int c = 0; c < 8; ++c) {
            float2 p;
            p.x = accm[j][2*c]   * (1.0f/H_DIM);
            p.y = accm[j][2*c+1] * (1.0f/H_DIM);
            *(float2*)&attn_mean[((size_t)b*T_DIM + t0 + row)*S_DIM + lane*2 + 128*c] = p;
        }
    }
}

// ---------------------------------------------------------------------------
// k2 = (khi+klo) + o_s, re-split in place.  grid 4096, block 256.
// ---------------------------------------------------------------------------
__global__ __launch_bounds__(256)
void add_k(unsigned short* __restrict__ Khi, unsigned short* __restrict__ Klo,
           const float* __restrict__ O)
{
    size_t i = ((size_t)blockIdx.x*256 + threadIdx.x)*8;
    short8 hi = *(short8*)(Khi+i), lo = *(short8*)(Klo+i);
    float4 o0 = *(const float4*)(O+i), o1 = *(const float4*)(O+i+4);
    float ov[8] = {o0.x,o0.y,o0.z,o0.w,o1.x,o1.y,o1.z,o1.w};
    short8 nh, nl;
    #pragma unroll
    for (int j = 0; j < 8; ++j) {
        float k = bf2f((unsigned short)hi[j]) + bf2f((unsigned short)lo[j]) + ov[j];
        unsigned short hh = f2bf(k);
        nh[j] = (short)hh;
        nl[j] = (short)f2bf(k - bf2f(hh));
    }
    *(short8*)(Khi+i) = nh;
    *(short8*)(Klo+i) = nl;
}

// v2 = v + o_s (fp32 in place).  grid 8192, block 256.
__global__ __launch_bounds__(256)
void add_v(float* __restrict__ V, const float* __restrict__ O)
{
    size_t i = ((size_t)blockIdx.x*256 + threadIdx.x)*4;
    float4 o = *(const float4*)(O+i);
    float4 v = *(const float4*)(V+i);
    v.x+=o.x; v.y+=o.y; v.z+=o.z; v.w+=o.w;
    *(float4*)(V+i) = v;
}

// ---------------------------------------------------------------------------
// Output projection (unchanged fp32): C = merge(O) @ ow^T.  grid (8,64,2).
// ---------------------------------------------------------------------------
__global__ __launch_bounds__(256)
void outproj_kernel(const float* __restrict__ Od, const float* __restrict__ Os,
                    const float* __restrict__ ow,
                    float* __restrict__ outd, float* __restrict__ outs)
{
    const int z = blockIdx.z;
    const float* Ain = z ? Os : Od;
    float* Out       = z ? outs : outd;

    __shared__ float As[16][132];
    __shared__ float Bs[16][132];

    const int tid = threadIdx.x;
    const int m0 = blockIdx.y * 128;
    const int n0 = blockIdx.x * 128;

    const int lrow = tid >> 1;
    const int lk   = (tid & 1) * 8;
    const int tx = tid & 15;
    const int ty = tid >> 4;

    const int r_ld = m0 + lrow;
    const int tt = r_ld >> 3;
    const int bb_ld = r_ld & 7;

    float acc[8][8];
    #pragma unroll
    for (int i = 0; i < 8; ++i)
        #pragma unroll
        for (int j = 0; j < 8; ++j) acc[i][j] = 0.f;

    const float* Wrow = ow + (size_t)(n0 + lrow)*E_DIM + lk;

    for (int kk = 0; kk < E_DIM; kk += 16) {
        const int k0 = kk + lk;
        const int h0 = k0 >> 6;
        const int d0 = k0 & 63;
        const float* ap = Ain + (((size_t)(bb_ld*H_DIM + h0)*T_DIM) + tt)*D_DIM + d0;
        float4 a0 = *(const float4*)ap;
        float4 a1 = *(const float4*)(ap + 4);
        float4 b0 = *(const float4*)(Wrow + kk);
        float4 b1 = *(const float4*)(Wrow + kk + 4);
        __syncthreads();
        As[lk+0][lrow]=a0.x; As[lk+1][lrow]=a0.y; As[lk+2][lrow]=a0.z; As[lk+3][lrow]=a0.w;
        As[lk+4][lrow]=a1.x; As[lk+5][lrow]=a1.y; As[lk+6][lrow]=a1.z; As[lk+7][lrow]=a1.w;
        Bs[lk+0][lrow]=b0.x; Bs[lk+1][lrow]=b0.y; Bs[lk+2][lrow]=b0.z; Bs[lk+3][lrow]=b0.w;
        Bs[lk+4][lrow]=b1.x; Bs[lk+5][lrow]=b1.y; Bs[lk+6][lrow]=b1.z; Bs[lk+7][lrow]=b1.w;
        __syncthreads();
        #pragma unroll
        for (int k = 0; k < 16; ++k) {
            float4 av0 = *(const float4*)&As[k][ty*8];
            float4 av1 = *(const float4*)&As[k][ty*8+4];
            float4 bv0 = *(const float4*)&Bs[k][tx*8];
            float4 bv1 = *(const float4*)&Bs[k][tx*8+4];
            float a[8] = {av0.x,av0.y,av0.z,av0.w,av1.x,av1.y,av1.z,av1.w};
            float b[8] = {bv0.x,bv0.y,bv0.z,bv0.w,bv1.x,bv1.y,bv1.z,bv1.w};
            #pragma unroll
            for (int i = 0; i < 8; ++i)
                #pragma unroll
                for (int j = 0; j < 8; ++j) acc[i][j] += a[i]*b[j];
        }
    }

    #pragma unroll
    for (int i = 0; i < 8; ++i) {
        int r = m0 + ty*8 + i;
        float* dst = Out + (size_t)r*E_DIM + n0 + tx*8;
        *(float4*)dst     = make_float4(acc[i][0],acc[i][1],acc[i][2],acc[i][3]);
        *(float4*)(dst+4) = make_float4(acc[i][4],acc[i][5],acc[i][6],acc[i][7]);
    }
}

// ---------------------------------------------------------------------------
extern "C" void kernel_launch(void* const* d_in, const int* in_sizes, int n_in,
                              void* d_out, int out_size, void* d_ws, size_t ws_size,
                              hipStream_t stream)
{
    const float* q1  = (const float*)d_in[0];
    const float* q2  = (const float*)d_in[1];
    const float* key = (const float*)d_in[2];
    const float* val = (const float*)d_in[3];
    // d_in[4] = attn_mask (causal triu k=1) computed analytically (s > t)
    const float* qw  = (const float*)d_in[5];
    const float* kw  = (const float*)d_in[6];
    const float* vw  = (const float*)d_in[7];
    const float* ow  = (const float*)d_in[8];

    float* out   = (float*)d_out;
    float* outd  = out;                    // attn_output_d [T,B,E]
    float* attnd = out + 1*(size_t)NBHTD;  // attn_d [B,T,S] (borrowed as Vh until attn_d)
    float* outs  = out + 2*(size_t)NBHTD;  // attn_output_s (borrowed as Q2h)
    float* attns = out + 3*(size_t)NBHTD;  // attn_s

    // ws layout (exactly 128 MB):
    unsigned short* Khi  = (unsigned short*)d_ws;          // 16 MB
    unsigned short* Klo  = Khi  + (size_t)NBHTD;           // 16 MB
    unsigned short* Vthi = Klo  + (size_t)NBHTD;           // 16 MB  [B,H,D,S]
    unsigned short* Vtlo = Vthi + (size_t)NBHTD;           // 16 MB
    float* Osb = (float*)(Vtlo + (size_t)NBHTD);           // 32 MB
    float* Odb = Osb + (size_t)NBHTD;                      // 32 MB

    float* Vh  = attnd;   // fp32 V [B,H,S,D]; dead before attn_d writes attnd
    float* Q1h = outd;    // fp32 Q1 [B,H,T,D]; dead before outproj writes outd
    float* Q2h = outs;

    proj_kernel<<<dim3(8, 64, 4), 256, 0, stream>>>(q1, q2, key, val, qw, kw, vw,
                                                    Q1h, Q2h, Khi, Klo, Vh);
    split_vt<<<dim3(16, 128), 256, 0, stream>>>(Vh, Vthi, Vtlo);
    attn_mfma<<<dim3(64, 8), 256, 0, stream>>>(Q2h, Khi, Klo, Vthi, Vtlo, Osb, attns);
    add_k<<<4096, 256, 0, stream>>>(Khi, Klo, Osb);
    add_v<<<8192, 256, 0, stream>>>(Vh, Osb);
    split_vt<<<dim3(16, 128), 256, 0, stream>>>(Vh, Vthi, Vtlo);
    attn_mfma<<<dim3(64, 8), 256, 0, stream>>>(Q1h, Khi, Klo, Vthi, Vtlo, Odb, attnd);
    outproj_kernel<<<dim3(8, 64, 2), 256, 0, stream>>>(Odb, Osb, ow, outd, outs);
}

// Round 3
// 1908.454 us; speedup vs baseline: 2.7466x; 1.3473x over previous
//
#include <hip/hip_runtime.h>
#include <cstddef>

#define T_DIM 1024
#define S_DIM 1024
#define B_DIM 8
#define E_DIM 1024
#define H_DIM 16
#define D_DIM 64
#define NBHTD (B_DIM*H_DIM*T_DIM*D_DIM)   // 8388608 elements per [B,H,T,D] tensor

typedef __attribute__((ext_vector_type(8))) short short8;
typedef __attribute__((ext_vector_type(4))) float floatx4;

// ---- bf16 helpers (RNE via bit ops; no NaN inputs here) ----
__device__ inline unsigned short f2bf(float x){
    union { float f; unsigned u; } v; v.f = x;
    unsigned r = (v.u + 0x7FFFu + ((v.u >> 16) & 1u)) >> 16;
    return (unsigned short)r;
}
__device__ inline float bf2f(unsigned short h){
    union { float f; unsigned u; } v; v.u = ((unsigned)h) << 16; return v.f;
}

// async global->LDS, 16B per lane
typedef __attribute__((address_space(1))) const unsigned int* gptr_t;
typedef __attribute__((address_space(3))) unsigned int* lptr_t;
__device__ inline void gl_lds16(const void* g, void* l){
    __builtin_amdgcn_global_load_lds((gptr_t)g, (lptr_t)l, 16, 0, 0);
}

// LDS swizzle for the 16x1024 fp32 score/prob buffer (attn)
__device__ inline int swz(int row, int s){
    int ch = (s >> 2) ^ (row & 7);
    return (row << 10) + (ch << 2) + (s & 3);
}

// ---------------------------------------------------------------------------
// Element-wise bf16 hi/lo split (optionally scaled): x -> hi=bf16(x),
// lo=bf16(x-hi).  8 elems/thread.
// ---------------------------------------------------------------------------
__global__ __launch_bounds__(256)
void split_pair(const float* __restrict__ src, unsigned short* __restrict__ hi,
                unsigned short* __restrict__ lo, float scale)
{
    size_t i = ((size_t)blockIdx.x*256 + threadIdx.x)*8;
    float4 a = *(const float4*)(src+i);
    float4 b = *(const float4*)(src+i+4);
    float v[8] = {a.x,a.y,a.z,a.w,b.x,b.y,b.z,b.w};
    short8 h8, l8;
    #pragma unroll
    for (int j = 0; j < 8; ++j) {
        float x = v[j]*scale;
        unsigned short hh = f2bf(x);
        h8[j] = (short)hh;
        l8[j] = (short)f2bf(x - bf2f(hh));
    }
    *(short8*)(hi+i) = h8;
    *(short8*)(lo+i) = l8;
}

// ---------------------------------------------------------------------------
// bf16x3 MFMA GEMM: C[m,n] = sum_k A[m,k]*B[n,k], M=8192, N=K=1024.
// A,B pre-split bf16 hi/lo.  acc += Ah*Bh + Ah*Bl + Al*Bh  (rel err ~2^-17).
// AMODE 0: A row-major [8192,1024]. AMODE 1: A gathered from [B,H,T,D]
//   (row r = t*8+b, col e = h*64+d).
// CMODE 0: Cf fp32 scatter to [B,H,T,D].  CMODE 1: split bf16 hi/lo scatter
//   to [B,H,T,D].  CMODE 2: Cf fp32 row-major [8192,1024].
// 128x128 tile, BK=32, block 256 (4 waves, 2x2), grid (8, 64).
// ---------------------------------------------------------------------------
template <int AMODE, int CMODE>
__global__ __launch_bounds__(256, 2)
void gemm_bf3(const unsigned short* __restrict__ Ahi, const unsigned short* __restrict__ Alo,
              const unsigned short* __restrict__ Bhi, const unsigned short* __restrict__ Blo,
              float* __restrict__ Cf,
              unsigned short* __restrict__ Chi, unsigned short* __restrict__ Clo)
{
    __shared__ __align__(16) unsigned short lds[4][128*32];  // Ahi,Alo,Bhi,Blo 8KB each

    const int tid  = threadIdx.x;
    const int n0   = blockIdx.x * 128;
    const int m0   = blockIdx.y * 128;
    const int wave = tid >> 6, lane = tid & 63;
    const int lrow = lane & 15, quad = lane >> 4;
    const int mw = (wave & 1)*64, nw = (wave >> 1)*64;

    floatx4 acc[4][4];
    #pragma unroll
    for (int i = 0; i < 4; ++i)
        #pragma unroll
        for (int j = 0; j < 4; ++j) acc[i][j] = (floatx4){0.f,0.f,0.f,0.f};

    for (int kk = 0; kk < 1024; kk += 32) {
        __syncthreads();
        #pragma unroll
        for (int rnd = 0; rnd < 2; ++rnd) {
            int c = rnd*256 + tid;
            int row = c >> 2, col8 = (c & 3)*8;
            size_t aoff;
            if (AMODE == 0) {
                aoff = (size_t)(m0+row)*1024 + kk + col8;
            } else {
                int r = m0 + row; int t = r >> 3, bb = r & 7;
                int h = kk >> 6, d0 = (kk & 63) + col8;
                aoff = (((size_t)(bb*H_DIM + h)*T_DIM) + t)*D_DIM + d0;
            }
            size_t boff = (size_t)(n0+row)*1024 + kk + col8;
            gl_lds16(Ahi + aoff, &lds[0][c*8]);
            gl_lds16(Alo + aoff, &lds[1][c*8]);
            gl_lds16(Bhi + boff, &lds[2][c*8]);
            gl_lds16(Blo + boff, &lds[3][c*8]);
        }
        __syncthreads();

        short8 ah[4], al[4], bh[4], bl[4];
        #pragma unroll
        for (int mt = 0; mt < 4; ++mt) {
            int r = mw + mt*16 + lrow;
            ah[mt] = *(const short8*)&lds[0][r*32 + quad*8];
            al[mt] = *(const short8*)&lds[1][r*32 + quad*8];
        }
        #pragma unroll
        for (int nt = 0; nt < 4; ++nt) {
            int r = nw + nt*16 + lrow;
            bh[nt] = *(const short8*)&lds[2][r*32 + quad*8];
            bl[nt] = *(const short8*)&lds[3][r*32 + quad*8];
        }
        #pragma unroll
        for (int mt = 0; mt < 4; ++mt)
            #pragma unroll
            for (int nt = 0; nt < 4; ++nt) {
                acc[mt][nt] = __builtin_amdgcn_mfma_f32_16x16x32_bf16(ah[mt], bh[nt], acc[mt][nt], 0,0,0);
                acc[mt][nt] = __builtin_amdgcn_mfma_f32_16x16x32_bf16(ah[mt], bl[nt], acc[mt][nt], 0,0,0);
                acc[mt][nt] = __builtin_amdgcn_mfma_f32_16x16x32_bf16(al[mt], bh[nt], acc[mt][nt], 0,0,0);
            }
    }

    // epilogue: C row m = quad*4+r within tile, col n = lrow within tile
    #pragma unroll
    for (int mt = 0; mt < 4; ++mt) {
        #pragma unroll
        for (int nt = 0; nt < 4; ++nt) {
            int n = n0 + nw + nt*16 + lrow;
            #pragma unroll
            for (int r = 0; r < 4; ++r) {
                int m = m0 + mw + mt*16 + quad*4 + r;
                float v = acc[mt][nt][r];
                if (CMODE == 2) {
                    Cf[(size_t)m*1024 + n] = v;
                } else {
                    int t = m >> 3, bb = m & 7;
                    int h = n >> 6, d = n & 63;
                    size_t idx = (((size_t)(bb*H_DIM + h)*T_DIM) + t)*D_DIM + d;
                    if (CMODE == 0) {
                        Cf[idx] = v;
                    } else {
                        unsigned short hh = f2bf(v);
                        Chi[idx] = hh;
                        Clo[idx] = f2bf(v - bf2f(hh));
                    }
                }
            }
        }
    }
}

// ---------------------------------------------------------------------------
// Split+transpose V: fp32 [B,H,S,D] -> bf16 hi/lo [B,H,D,S].
// grid (16, 128), block 256.
// ---------------------------------------------------------------------------
__global__ __launch_bounds__(256)
void split_vt(const float* __restrict__ Vh, unsigned short* __restrict__ Vthi,
              unsigned short* __restrict__ Vtlo)
{
    __shared__ float tile[64][68];
    const int bh = blockIdx.y, s0 = blockIdx.x*64;
    const int tid = threadIdx.x;
    const size_t base = (size_t)bh*S_DIM*D_DIM;

    {
        int r = tid >> 2, c0 = (tid & 3) * 16;
        const float* p = Vh + base + (size_t)(s0 + r)*D_DIM + c0;
        float4 a = *(const float4*)p;
        float4 b = *(const float4*)(p+4);
        float4 c = *(const float4*)(p+8);
        float4 d = *(const float4*)(p+12);
        *(float4*)&tile[r][c0]    = a;
        *(float4*)&tile[r][c0+4]  = b;
        *(float4*)&tile[r][c0+8]  = c;
        *(float4*)&tile[r][c0+12] = d;
    }
    __syncthreads();
    {
        int d = tid >> 2, cs = (tid & 3) * 16;
        short8 hi[2], lo[2];
        #pragma unroll
        for (int half = 0; half < 2; ++half)
            #pragma unroll
            for (int u = 0; u < 8; ++u) {
                float x = tile[cs + half*8 + u][d];
                unsigned short hh = f2bf(x);
                hi[half][u] = (short)hh;
                lo[half][u] = (short)f2bf(x - bf2f(hh));
            }
        size_t obase = base + (size_t)d*S_DIM + s0 + cs;
        *(short8*)(Vthi + obase)     = hi[0];
        *(short8*)(Vthi + obase + 8) = hi[1];
        *(short8*)(Vtlo + obase)     = lo[0];
        *(short8*)(Vtlo + obase + 8) = lo[1];
    }
}

// ---------------------------------------------------------------------------
// MFMA attention pass (one stream), bf16x3 scores / bf16x2 PV.
// Emits O as fp32 (optional) AND bf16 hi/lo split (for the MFMA out-proj).
// grid (64, 8), block 256, LDS 64KB.
// ---------------------------------------------------------------------------
__global__ __launch_bounds__(256, 2)
void attn_mfma(const float* __restrict__ Qh,
               const unsigned short* __restrict__ Khi, const unsigned short* __restrict__ Klo,
               const unsigned short* __restrict__ Vthi, const unsigned short* __restrict__ Vtlo,
               float* __restrict__ Ofp,
               unsigned short* __restrict__ Ohi, unsigned short* __restrict__ Olo,
               float* __restrict__ attn_mean)
{
    const int b  = blockIdx.y;
    const int t0 = blockIdx.x * 16;
    const int tid  = threadIdx.x;
    const int lane = tid & 63;
    const int wave = tid >> 6;
    const int lrow = lane & 15;
    const int quad = lane >> 4;

    __shared__ float sc[16 * 1024];   // 64 KB, swizzled

    float accm[4][16];
    #pragma unroll
    for (int j = 0; j < 4; ++j)
        #pragma unroll
        for (int c = 0; c < 16; ++c) accm[j][c] = 0.f;

    #pragma unroll 1
    for (int h = 0; h < H_DIM; ++h) {
        const int bh = b*H_DIM + h;
        const size_t kbase = (size_t)bh * S_DIM * D_DIM;

        // ---- Q fragments (A-layout), bf16 hi/lo, k0 = 0 and 32 ----
        short8 qh0, ql0, qh1, ql1;
        {
            const float* qp = Qh + kbase + (size_t)(t0 + lrow)*D_DIM + quad*8;
            float4 a  = *(const float4*)qp;
            float4 b4 = *(const float4*)(qp+4);
            float4 c4 = *(const float4*)(qp+32);
            float4 d4 = *(const float4*)(qp+36);
            float va[8] = {a.x,a.y,a.z,a.w,b4.x,b4.y,b4.z,b4.w};
            float vb8[8] = {c4.x,c4.y,c4.z,c4.w,d4.x,d4.y,d4.z,d4.w};
            #pragma unroll
            for (int j = 0; j < 8; ++j) {
                unsigned short h0 = f2bf(va[j]);
                qh0[j] = (short)h0; ql0[j] = (short)f2bf(va[j] - bf2f(h0));
                unsigned short h1 = f2bf(vb8[j]);
                qh1[j] = (short)h1; ql1[j] = (short)f2bf(vb8[j] - bf2f(h1));
            }
        }

        __syncthreads();   // sc free (previous head's PV reads done)

        // ---- scores: wave w covers s in [w*256,(w+1)*256), 16 tiles ----
        #pragma unroll 1
        for (int jt = 0; jt < 16; ++jt) {
            const int s0 = wave*256 + jt*16;
            const unsigned short* kp_h = Khi + kbase + (size_t)(s0 + lrow)*D_DIM + quad*8;
            const unsigned short* kp_l = Klo + kbase + (size_t)(s0 + lrow)*D_DIM + quad*8;
            short8 kh0 = *(const short8*)(kp_h);
            short8 kh1 = *(const short8*)(kp_h + 32);
            short8 kl0 = *(const short8*)(kp_l);
            short8 kl1 = *(const short8*)(kp_l + 32);
            floatx4 acc = {0.f,0.f,0.f,0.f};
            acc = __builtin_amdgcn_mfma_f32_16x16x32_bf16(qh0, kh0, acc, 0,0,0);
            acc = __builtin_amdgcn_mfma_f32_16x16x32_bf16(qh1, kh1, acc, 0,0,0);
            acc = __builtin_amdgcn_mfma_f32_16x16x32_bf16(qh0, kl0, acc, 0,0,0);
            acc = __builtin_amdgcn_mfma_f32_16x16x32_bf16(qh1, kl1, acc, 0,0,0);
            acc = __builtin_amdgcn_mfma_f32_16x16x32_bf16(ql0, kh0, acc, 0,0,0);
            acc = __builtin_amdgcn_mfma_f32_16x16x32_bf16(ql1, kh1, acc, 0,0,0);
            const int s_g = s0 + lrow;
            #pragma unroll
            for (int r = 0; r < 4; ++r) {
                int q = quad*4 + r;
                float v = (s_g > t0 + q) ? 1e-30f : acc[r];
                sc[swz(q, s_g)] = v;
            }
        }
        __syncthreads();

        // ---- softmax (+ fused head-mean accumulate) ----
        #pragma unroll 1
        for (int j = 0; j < 4; ++j) {
            const int row = wave*4 + j;
            float2 vb[8];
            float m = -3.0e38f;
            #pragma unroll
            for (int c = 0; c < 8; ++c) {
                int s = lane*2 + 128*c;
                vb[c] = *(const float2*)&sc[swz(row, s)];
                m = fmaxf(m, fmaxf(vb[c].x, vb[c].y));
            }
            #pragma unroll
            for (int off = 32; off > 0; off >>= 1) m = fmaxf(m, __shfl_xor(m, off));
            float sum = 0.f;
            #pragma unroll
            for (int c = 0; c < 8; ++c) {
                vb[c].x = __expf(vb[c].x - m);
                vb[c].y = __expf(vb[c].y - m);
                sum += vb[c].x + vb[c].y;
            }
            #pragma unroll
            for (int off = 32; off > 0; off >>= 1) sum += __shfl_xor(sum, off);
            const float inv = 1.0f / sum;
            #pragma unroll
            for (int c = 0; c < 8; ++c) {
                int s = lane*2 + 128*c;
                float p0 = vb[c].x * inv, p1 = vb[c].y * inv;
                accm[j][2*c]   += p0;
                accm[j][2*c+1] += p1;
                float2 pw; pw.x = p0; pw.y = p1;
                *(float2*)&sc[swz(row, s)] = pw;
            }
        }
        __syncthreads();

        // ---- PV: wave w owns d-block [16w,16w+16) ----
        {
            const int d0 = wave*16;
            const unsigned short* vh = Vthi + kbase + (size_t)(d0 + lrow)*S_DIM;
            const unsigned short* vl = Vtlo + kbase + (size_t)(d0 + lrow)*S_DIM;
            floatx4 oa = {0.f,0.f,0.f,0.f}, ob = {0.f,0.f,0.f,0.f};
            #pragma unroll 2
            for (int sk = 0; sk < S_DIM; sk += 32) {
                const int sa = sk + quad*8;
                float4 p0 = *(const float4*)&sc[swz(lrow, sa)];
                float4 p1 = *(const float4*)&sc[swz(lrow, sa+4)];
                short8 af;
                af[0]=(short)f2bf(p0.x); af[1]=(short)f2bf(p0.y);
                af[2]=(short)f2bf(p0.z); af[3]=(short)f2bf(p0.w);
                af[4]=(short)f2bf(p1.x); af[5]=(short)f2bf(p1.y);
                af[6]=(short)f2bf(p1.z); af[7]=(short)f2bf(p1.w);
                short8 bh8 = *(const short8*)(vh + sa);
                short8 bl8 = *(const short8*)(vl + sa);
                oa = __builtin_amdgcn_mfma_f32_16x16x32_bf16(af, bh8, oa, 0,0,0);
                ob = __builtin_amdgcn_mfma_f32_16x16x32_bf16(af, bl8, ob, 0,0,0);
            }
            #pragma unroll
            for (int r = 0; r < 4; ++r) {
                int q = quad*4 + r;
                float v = oa[r] + ob[r];
                size_t idx = kbase + (size_t)(t0+q)*D_DIM + d0 + lrow;
                if (Ofp) Ofp[idx] = v;
                unsigned short hh = f2bf(v);
                Ohi[idx] = hh;
                Olo[idx] = f2bf(v - bf2f(hh));
            }
        }
    }

    // ---- head-mean write: [B,T,S] ----
    #pragma unroll
    for (int j = 0; j < 4; ++j) {
        int row = wave*4 + j;
        #pragma unroll
        for (int c = 0; c < 8; ++c) {
            float2 p;
            p.x = accm[j][2*c]   * (1.0f/H_DIM);
            p.y = accm[j][2*c+1] * (1.0f/H_DIM);
            *(float2*)&attn_mean[((size_t)b*T_DIM + t0 + row)*S_DIM + lane*2 + 128*c] = p;
        }
    }
}

// ---------------------------------------------------------------------------
// k2 = (khi+klo) + o_s, re-split in place.  grid 4096, block 256.
// ---------------------------------------------------------------------------
__global__ __launch_bounds__(256)
void add_k(unsigned short* __restrict__ Khi, unsigned short* __restrict__ Klo,
           const float* __restrict__ O)
{
    size_t i = ((size_t)blockIdx.x*256 + threadIdx.x)*8;
    short8 hi = *(short8*)(Khi+i), lo = *(short8*)(Klo+i);
    float4 o0 = *(const float4*)(O+i), o1 = *(const float4*)(O+i+4);
    float ov[8] = {o0.x,o0.y,o0.z,o0.w,o1.x,o1.y,o1.z,o1.w};
    short8 nh, nl;
    #pragma unroll
    for (int j = 0; j < 8; ++j) {
        float k = bf2f((unsigned short)hi[j]) + bf2f((unsigned short)lo[j]) + ov[j];
        unsigned short hh = f2bf(k);
        nh[j] = (short)hh;
        nl[j] = (short)f2bf(k - bf2f(hh));
    }
    *(short8*)(Khi+i) = nh;
    *(short8*)(Klo+i) = nl;
}

// v2 = v + o_s (fp32 in place).  grid 8192, block 256.
__global__ __launch_bounds__(256)
void add_v(float* __restrict__ V, const float* __restrict__ O)
{
    size_t i = ((size_t)blockIdx.x*256 + threadIdx.x)*4;
    float4 o = *(const float4*)(O+i);
    float4 v = *(const float4*)(V+i);
    v.x+=o.x; v.y+=o.y; v.z+=o.z; v.w+=o.w;
    *(float4*)(V+i) = v;
}

// ---------------------------------------------------------------------------
extern "C" void kernel_launch(void* const* d_in, const int* in_sizes, int n_in,
                              void* d_out, int out_size, void* d_ws, size_t ws_size,
                              hipStream_t stream)
{
    const float* q1  = (const float*)d_in[0];
    const float* q2  = (const float*)d_in[1];
    const float* key = (const float*)d_in[2];
    const float* val = (const float*)d_in[3];
    // d_in[4] = attn_mask (causal triu k=1) computed analytically (s > t)
    const float* qw  = (const float*)d_in[5];
    const float* kw  = (const float*)d_in[6];
    const float* vw  = (const float*)d_in[7];
    const float* ow  = (const float*)d_in[8];

    float* out   = (float*)d_out;
    float* outd  = out;                    // attn_output_d [T,B,E]
    float* attnd = out + 1*(size_t)NBHTD;  // attn_d [B,T,S]
    float* outs  = out + 2*(size_t)NBHTD;  // attn_output_s
    float* attns = out + 3*(size_t)NBHTD;  // attn_s

    // ---- ws layout (exactly 128 MiB = 8*NBHTD ushorts) ----
    unsigned short* ws_u16 = (unsigned short*)d_ws;
    unsigned short* Khi  = ws_u16;                     // R1: 4*NBHTD u16
    unsigned short* Klo  = Khi  + (size_t)NBHTD;
    unsigned short* Vthi = Klo  + (size_t)NBHTD;
    unsigned short* Vtlo = Vthi + (size_t)NBHTD;
    unsigned short* R2a  = Vtlo + (size_t)NBHTD;       // 2*NBHTD u16 (33.5 MB)
    unsigned short* R2b  = R2a  + 2*(size_t)NBHTD;     // 2*NBHTD u16

    // phase-1 overlays of R2a: weight splits (qw,kw,vw)
    const size_t EE = (size_t)E_DIM*E_DIM;
    unsigned short* qwhi = R2a;
    unsigned short* qwlo = qwhi + EE;
    unsigned short* kwhi = qwlo + EE;
    unsigned short* kwlo = kwhi + EE;
    unsigned short* vwhi = kwlo + EE;
    unsigned short* vwlo = vwhi + EE;
    // phase-2/3 overlay of R2a: o_s fp32
    float* Osb = (float*)R2a;
    // phase-4 overlay of R2a: o_d split
    unsigned short* Odhi = R2a;
    unsigned short* Odlo = Odhi + (size_t)NBHTD;
    // R2b: o_s split (attn#1 -> outproj)
    unsigned short* Oshi = R2b;
    unsigned short* Oslo = Oshi + (size_t)NBHTD;
    // phase-5 overlay of R1 (K/V splits dead): ow split
    unsigned short* owhi = ws_u16;
    unsigned short* owlo = owhi + EE;

    // d_out borrowing:
    float* Q1h = outd;    // fp32 [B,H,T,D], dead before outproj writes outd
    float* Q2h = outs;    // dead before outproj writes outs
    float* Vh  = attnd;   // fp32 V, dead before attn#2 writes attnd
    unsigned short* Ahi = (unsigned short*)attns;   // A-split arena (phase 1)
    unsigned short* Alo = Ahi + (size_t)NBHTD;      // dead before attn#1 writes attns

    const dim3 ggrid(8, 64);

    // ---- phase 1: projections (bf16x3 MFMA) ----
    split_pair<<<512, 256, 0, stream>>>(qw, qwhi, qwlo, 1.f);
    split_pair<<<512, 256, 0, stream>>>(kw, kwhi, kwlo, 1.f);
    split_pair<<<512, 256, 0, stream>>>(vw, vwhi, vwlo, 1.f);

    split_pair<<<4096, 256, 0, stream>>>(key, Ahi, Alo, 1.f);
    gemm_bf3<0,1><<<ggrid, 256, 0, stream>>>(Ahi, Alo, kwhi, kwlo, nullptr, Khi, Klo);

    split_pair<<<4096, 256, 0, stream>>>(val, Ahi, Alo, 1.f);
    gemm_bf3<0,0><<<ggrid, 256, 0, stream>>>(Ahi, Alo, vwhi, vwlo, Vh, nullptr, nullptr);
    split_vt<<<dim3(16, 128), 256, 0, stream>>>(Vh, Vthi, Vtlo);

    split_pair<<<4096, 256, 0, stream>>>(q1, Ahi, Alo, 0.125f);
    gemm_bf3<0,0><<<ggrid, 256, 0, stream>>>(Ahi, Alo, qwhi, qwlo, Q1h, nullptr, nullptr);

    split_pair<<<4096, 256, 0, stream>>>(q2, Ahi, Alo, 0.125f);
    gemm_bf3<0,0><<<ggrid, 256, 0, stream>>>(Ahi, Alo, qwhi, qwlo, Q2h, nullptr, nullptr);

    // ---- phase 2: stream s ----
    attn_mfma<<<dim3(64, 8), 256, 0, stream>>>(Q2h, Khi, Klo, Vthi, Vtlo,
                                               Osb, Oshi, Oslo, attns);

    // ---- phase 3: k/v update ----
    add_k<<<4096, 256, 0, stream>>>(Khi, Klo, Osb);
    add_v<<<8192, 256, 0, stream>>>(Vh, Osb);
    split_vt<<<dim3(16, 128), 256, 0, stream>>>(Vh, Vthi, Vtlo);

    // ---- phase 4: stream d ----
    attn_mfma<<<dim3(64, 8), 256, 0, stream>>>(Q1h, Khi, Klo, Vthi, Vtlo,
                                               nullptr, Odhi, Odlo, attnd);

    // ---- phase 5: output projections ----
    split_pair<<<512, 256, 0, stream>>>(ow, owhi, owlo, 1.f);
    gemm_bf3<1,2><<<ggrid, 256, 0, stream>>>(Oshi, Oslo, owhi, owlo, outs, nullptr, nullptr);
    gemm_bf3<1,2><<<ggrid, 256, 0, stream>>>(Odhi, Odlo, owhi, owlo, outd, nullptr, nullptr);
}